// Round 2
// baseline (1359.837 us; speedup 1.0000x reference)
//
#include <hip/hip_runtime.h>

typedef unsigned short u16;
typedef unsigned int u32;
typedef __bf16 bf16x8 __attribute__((ext_vector_type(8)));
typedef float f32x4 __attribute__((ext_vector_type(4)));

#define MFMA16(a, b, c) __builtin_amdgcn_mfma_f32_16x16x32_bf16(a, b, c, 0, 0, 0)

__device__ __forceinline__ u16 f2bf(float f) {
  u32 u = __builtin_bit_cast(u32, f);
  u32 r = u + 0x7fffu + ((u >> 16) & 1u);
  return (u16)(r >> 16);
}

__device__ __forceinline__ uint4 cvt8(const float4& a, const float4& b) {
  union { u16 h[8]; uint4 q; } u;
  u.h[0] = f2bf(a.x); u.h[1] = f2bf(a.y); u.h[2] = f2bf(a.z); u.h[3] = f2bf(a.w);
  u.h[4] = f2bf(b.x); u.h[5] = f2bf(b.y); u.h[6] = f2bf(b.z); u.h[7] = f2bf(b.w);
  return u.q;
}

__device__ __forceinline__ void ln4(float4& v, float m, float r,
                                    const float4& w, const float4& b) {
  v.x = (v.x - m) * r * w.x + b.x;
  v.y = (v.y - m) * r * w.y + b.y;
  v.z = (v.z - m) * r * w.z + b.z;
  v.w = (v.w - m) * r * w.w + b.w;
}

// ---------------------------------------------------------------------------
// 128x128-tile bf16 MFMA GEMM: C = A(MxK, lda) * W(NxK, ldb)^T, fused epilogue
// ASRC 0: A is bf16;  1: A is f32 + LayerNorm(mu,rs,lnw,lnb);  2: A is f32
// MODE 0: +bias, store bf16               (qkv)
// MODE 1: +bias +aux0(x f32), store f32   (out_proj -> x1 in d_out)
// MODE 2: +bias, relu, *gates, bf16       (adapter down -> hg)
// MODE 3: outF += 0.1*(acc + gb)          (adapter up -> y into d_out)
// MODE 4: +bias, QuickGELU, bf16          (c_fc chunk -> h2c)
// MODE 5: outF += acc (+bias if chunk0)   (c_proj partial into d_out)
// ---------------------------------------------------------------------------
#define LDSS 40

template <int MODE, int ASRC>
__global__ __launch_bounds__(256) void gemm_k(
    const void* __restrict__ Av, int lda,
    const u16* __restrict__ W, int ldb,
    const float* __restrict__ bias, const float* __restrict__ aux0,
    const float* __restrict__ mu, const float* __restrict__ rs,
    const float* __restrict__ lnw, const float* __restrict__ lnb,
    float* __restrict__ outF, u16* __restrict__ outB, int N, int K)
{
  __shared__ u16 As[128 * LDSS];
  __shared__ u16 Bs[128 * LDSS];
  const int tid = threadIdx.x;
  const int m0 = blockIdx.y * 128, n0 = blockIdx.x * 128;
  const int w = tid >> 6, lane = tid & 63, lr = lane & 15, quad = lane >> 4;
  const int wm = (w >> 1) * 64, wn = (w & 1) * 64;

  f32x4 acc[4][4];
  #pragma unroll
  for (int i = 0; i < 4; i++)
    #pragma unroll
    for (int j = 0; j < 4; j++)
      #pragma unroll
      for (int r = 0; r < 4; r++) acc[i][j][r] = 0.f;

  const int r0 = tid >> 2, ch0 = (tid & 3) * 8;
  const u16* W1 = W + (long)(n0 + r0) * ldb + ch0;
  const u16* W2 = W + (long)(n0 + r0 + 64) * ldb + ch0;
  const u16* A1 = nullptr; const u16* A2 = nullptr;
  const float* F1 = nullptr; const float* F2 = nullptr;
  float mu1 = 0.f, rs1 = 0.f, mu2 = 0.f, rs2 = 0.f;
  if constexpr (ASRC == 0) {
    A1 = (const u16*)Av + (long)(m0 + r0) * lda + ch0;
    A2 = (const u16*)Av + (long)(m0 + r0 + 64) * lda + ch0;
  } else {
    F1 = (const float*)Av + (long)(m0 + r0) * lda + ch0;
    F2 = (const float*)Av + (long)(m0 + r0 + 64) * lda + ch0;
    if constexpr (ASRC == 1) {
      mu1 = mu[m0 + r0]; rs1 = rs[m0 + r0];
      mu2 = mu[m0 + r0 + 64]; rs2 = rs[m0 + r0 + 64];
    }
  }

  for (int k0 = 0; k0 < K; k0 += 32) {
    uint4 a0, a1;
    if constexpr (ASRC == 0) {
      a0 = *(const uint4*)(A1 + k0);
      a1 = *(const uint4*)(A2 + k0);
    } else {
      float4 p0 = *(const float4*)(F1 + k0);
      float4 p1 = *(const float4*)(F1 + k0 + 4);
      float4 q0 = *(const float4*)(F2 + k0);
      float4 q1 = *(const float4*)(F2 + k0 + 4);
      if constexpr (ASRC == 1) {
        float4 w0 = *(const float4*)(lnw + k0 + ch0);
        float4 w1 = *(const float4*)(lnw + k0 + ch0 + 4);
        float4 b0 = *(const float4*)(lnb + k0 + ch0);
        float4 b1 = *(const float4*)(lnb + k0 + ch0 + 4);
        ln4(p0, mu1, rs1, w0, b0); ln4(p1, mu1, rs1, w1, b1);
        ln4(q0, mu2, rs2, w0, b0); ln4(q1, mu2, rs2, w1, b1);
      }
      a0 = cvt8(p0, p1);
      a1 = cvt8(q0, q1);
    }
    uint4 b0v = *(const uint4*)(W1 + k0);
    uint4 b1v = *(const uint4*)(W2 + k0);
    __syncthreads();
    *(uint4*)&As[r0 * LDSS + ch0] = a0;
    *(uint4*)&As[(r0 + 64) * LDSS + ch0] = a1;
    *(uint4*)&Bs[r0 * LDSS + ch0] = b0v;
    *(uint4*)&Bs[(r0 + 64) * LDSS + ch0] = b1v;
    __syncthreads();
    bf16x8 bfr[4];
    #pragma unroll
    for (int j = 0; j < 4; j++)
      bfr[j] = *(const bf16x8*)&Bs[(wn + j * 16 + lr) * LDSS + quad * 8];
    #pragma unroll
    for (int i = 0; i < 4; i++) {
      bf16x8 af = *(const bf16x8*)&As[(wm + i * 16 + lr) * LDSS + quad * 8];
      #pragma unroll
      for (int j = 0; j < 4; j++)
        acc[i][j] = MFMA16(af, bfr[j], acc[i][j]);
    }
  }

  #pragma unroll
  for (int i = 0; i < 4; i++) {
    #pragma unroll
    for (int j = 0; j < 4; j++) {
      #pragma unroll
      for (int r = 0; r < 4; r++) {
        const int gm = m0 + wm + i * 16 + quad * 4 + r;
        const int gn = n0 + wn + j * 16 + lr;
        const long oidx = (long)gm * N + gn;
        float v = acc[i][j][r];
        if constexpr (MODE == 0) {
          v += bias[gn];
          outB[oidx] = f2bf(v);
        } else if constexpr (MODE == 1) {
          v += bias[gn] + aux0[oidx];
          outF[oidx] = v;
        } else if constexpr (MODE == 2) {
          v += bias[gn];
          v = fmaxf(v, 0.f);
          float g = aux0[(gm & 63) * 8 + (gn >> 6)];
          outB[oidx] = f2bf(v * g);
        } else if constexpr (MODE == 3) {
          outF[oidx] += 0.1f * (v + aux0[(gm & 63) * 1024 + gn]);
        } else if constexpr (MODE == 4) {
          v += bias[gn];
          v = v / (1.f + __expf(-1.702f * v));
          outB[oidx] = f2bf(v);
        } else {
          if (bias) v += bias[gn];
          outF[oidx] += v;
        }
      }
    }
  }
}

// ---------------------------------------------------------------------------
// Fused attention per (b,h): S=QK^T/8 -> softmax -> P*V; O overwrites q-slot.
// qkv: [tok=l*64+b][3072], q@+0, k@+1024, v@+2048, col h*64+d. LDS ~51KB.
// ---------------------------------------------------------------------------
__global__ __launch_bounds__(256) void attn_k(u16* __restrict__ qkv)
{
  __shared__ u16 Vt[64 * 264];
  __shared__ u16 Ps[32 * 264];
  __shared__ float rowstat[64];
  float* red = (float*)Ps;  // red's lifetime ends before Ps is written
  const int bh = blockIdx.x, b = bh >> 4, h = bh & 15;
  const int tid = threadIdx.x, w = tid >> 6, lane = tid & 63;
  const int lr = lane & 15, quad = lane >> 4;
  const long base = (long)b * 3072 + h * 64;

  // V -> LDS transposed: Vt[d][m]
  for (int c = tid; c < 2048; c += 256) {
    int m = c >> 3, ch = (c & 7) * 8;
    uint4 vv = *(const uint4*)(qkv + (long)m * 196608 + base + 2048 + ch);
    const u16* s = (const u16*)&vv;
    #pragma unroll
    for (int t = 0; t < 8; t++) Vt[(ch + t) * 264 + m] = s[t];
  }
  __syncthreads();

  for (int qb = 0; qb < 4; qb++) {
    f32x4 acc[4][4];
    #pragma unroll
    for (int i = 0; i < 4; i++)
      #pragma unroll
      for (int j = 0; j < 4; j++)
        #pragma unroll
        for (int r = 0; r < 4; r++) acc[i][j][r] = 0.f;

    // scores: wave w owns keys [w*64, w*64+64); K,Q fragments from global (L2)
    #pragma unroll
    for (int ks = 0; ks < 2; ks++) {
      bf16x8 bfr[4];
      #pragma unroll
      for (int j = 0; j < 4; j++) {
        int key = w * 64 + j * 16 + lr;
        bfr[j] = *(const bf16x8*)(qkv + (long)key * 196608 + base + 1024 + ks * 32 + quad * 8);
      }
      #pragma unroll
      for (int i = 0; i < 4; i++) {
        int gq = qb * 64 + i * 16 + lr;
        bf16x8 af = *(const bf16x8*)(qkv + (long)gq * 196608 + base + ks * 32 + quad * 8);
        #pragma unroll
        for (int j = 0; j < 4; j++)
          acc[i][j] = MFMA16(af, bfr[j], acc[i][j]);
      }
    }

    // row max (scale 1/8)
    #pragma unroll
    for (int i = 0; i < 4; i++) {
      #pragma unroll
      for (int r = 0; r < 4; r++) {
        float m = -1e30f;
        #pragma unroll
        for (int j = 0; j < 4; j++) {
          float s = acc[i][j][r] * 0.125f;
          acc[i][j][r] = s;
          m = fmaxf(m, s);
        }
        #pragma unroll
        for (int off = 1; off < 16; off <<= 1) m = fmaxf(m, __shfl_xor(m, off));
        if (lr == 0) red[w * 64 + i * 16 + quad * 4 + r] = m;
      }
    }
    __syncthreads();
    if (tid < 64)
      rowstat[tid] = fmaxf(fmaxf(red[tid], red[64 + tid]),
                           fmaxf(red[128 + tid], red[192 + tid]));
    __syncthreads();

    // exp + row sum
    #pragma unroll
    for (int i = 0; i < 4; i++) {
      #pragma unroll
      for (int r = 0; r < 4; r++) {
        float rm = rowstat[i * 16 + quad * 4 + r];
        float s = 0.f;
        #pragma unroll
        for (int j = 0; j < 4; j++) {
          float e = __expf(acc[i][j][r] - rm);
          acc[i][j][r] = e;
          s += e;
        }
        #pragma unroll
        for (int off = 1; off < 16; off <<= 1) s += __shfl_xor(s, off);
        if (lr == 0) red[w * 64 + i * 16 + quad * 4 + r] = s;
      }
    }
    __syncthreads();
    if (tid < 64)
      rowstat[tid] = red[tid] + red[64 + tid] + red[128 + tid] + red[192 + tid];
    __syncthreads();

    // two halves of 32 q-rows: normalize -> Ps -> P*V -> O into q-slot
    #pragma unroll
    for (int hf = 0; hf < 2; hf++) {
      #pragma unroll
      for (int ii = 0; ii < 2; ii++) {
        int i = hf * 2 + ii;
        #pragma unroll
        for (int r = 0; r < 4; r++) {
          int row = i * 16 + quad * 4 + r;
          float inv = 1.f / rowstat[row];
          #pragma unroll
          for (int j = 0; j < 4; j++)
            Ps[(row - hf * 32) * 264 + w * 64 + j * 16 + lr] =
                f2bf(acc[i][j][r] * inv);
        }
      }
      __syncthreads();
      f32x4 o[2];
      #pragma unroll
      for (int j2 = 0; j2 < 2; j2++)
        #pragma unroll
        for (int r = 0; r < 4; r++) o[j2][r] = 0.f;
      #pragma unroll
      for (int ks = 0; ks < 8; ks++) {
        bf16x8 af = *(const bf16x8*)&Ps[((w >> 1) * 16 + lr) * 264 + ks * 32 + quad * 8];
        #pragma unroll
        for (int j2 = 0; j2 < 2; j2++) {
          int j = (w & 1) * 2 + j2;
          bf16x8 bv = *(const bf16x8*)&Vt[(j * 16 + lr) * 264 + ks * 32 + quad * 8];
          o[j2] = MFMA16(af, bv, o[j2]);
        }
      }
      int l0 = qb * 64 + hf * 32 + (w >> 1) * 16 + quad * 4;
      #pragma unroll
      for (int j2 = 0; j2 < 2; j2++) {
        int j = (w & 1) * 2 + j2;
        #pragma unroll
        for (int r = 0; r < 4; r++)
          qkv[(long)(l0 + r) * 196608 + base + j * 16 + lr] = f2bf(o[j2][r]);
      }
      __syncthreads();
    }
  }
}

// --------------------------- LN1 stats (mu, rstd per token) ----------------
__global__ __launch_bounds__(256) void stats_k(const float* __restrict__ x,
                                               float* __restrict__ mu,
                                               float* __restrict__ rs)
{
  const int tok = blockIdx.x * 4 + (threadIdx.x >> 6);
  const int lane = threadIdx.x & 63;
  const float* xp = x + (long)tok * 1024;
  float s = 0.f, s2 = 0.f;
  #pragma unroll
  for (int t = 0; t < 4; t++) {
    float4 v = *(const float4*)(xp + t * 256 + lane * 4);
    s += v.x + v.y + v.z + v.w;
    s2 += v.x * v.x + v.y * v.y + v.z * v.z + v.w * v.w;
  }
  #pragma unroll
  for (int off = 32; off >= 1; off >>= 1) {
    s += __shfl_xor(s, off);
    s2 += __shfl_xor(s2, off);
  }
  if (lane == 0) {
    float m = s * (1.f / 1024.f);
    mu[tok] = m;
    rs[tok] = rsqrtf(s2 * (1.f / 1024.f) - m * m + 1e-5f);
  }
}

// --------------------------- LayerNorm (f32 -> bf16) -----------------------
__global__ __launch_bounds__(256) void ln_k(const float* __restrict__ x,
                                            const float* __restrict__ wt,
                                            const float* __restrict__ bs,
                                            u16* __restrict__ out)
{
  const int tok = blockIdx.x * 4 + (threadIdx.x >> 6);
  const int lane = threadIdx.x & 63;
  const float* xp = x + (long)tok * 1024;
  float4 v[4];
  float s = 0.f, s2 = 0.f;
  #pragma unroll
  for (int t = 0; t < 4; t++) {
    v[t] = *(const float4*)(xp + t * 256 + lane * 4);
    s += v[t].x + v[t].y + v[t].z + v[t].w;
    s2 += v[t].x * v[t].x + v[t].y * v[t].y + v[t].z * v[t].z + v[t].w * v[t].w;
  }
  #pragma unroll
  for (int off = 32; off >= 1; off >>= 1) {
    s += __shfl_xor(s, off);
    s2 += __shfl_xor(s2, off);
  }
  const float m = s * (1.f / 1024.f);
  const float rstd = rsqrtf(s2 * (1.f / 1024.f) - m * m + 1e-5f);
  u16* op = out + (long)tok * 1024;
  #pragma unroll
  for (int t = 0; t < 4; t++) {
    int d = t * 256 + lane * 4;
    float4 wv = *(const float4*)(wt + d);
    float4 bv = *(const float4*)(bs + d);
    union { u16 h[4]; uint2 q; } o;
    o.h[0] = f2bf((v[t].x - m) * rstd * wv.x + bv.x);
    o.h[1] = f2bf((v[t].y - m) * rstd * wv.y + bv.y);
    o.h[2] = f2bf((v[t].z - m) * rstd * wv.z + bv.z);
    o.h[3] = f2bf((v[t].w - m) * rstd * wv.w + bv.w);
    *(uint2*)(op + d) = o.q;
  }
}

// --------------------------- weight converts -------------------------------
__global__ void cvtk(const float* __restrict__ src, u16* __restrict__ dst, int n4)
{
  int i = blockIdx.x * 256 + threadIdx.x;
  if (i >= n4) return;
  float4 v = ((const float4*)src)[i];
  union { u16 h[4]; uint2 q; } o;
  o.h[0] = f2bf(v.x); o.h[1] = f2bf(v.y); o.h[2] = f2bf(v.z); o.h[3] = f2bf(v.w);
  ((uint2*)dst)[i] = o.q;
}

// dst[d*512 + e*64 + r] = up_w[(e*1024 + d)*64 + r]   (up_w is (E,D,R))
__global__ void wupk(const float* __restrict__ up_w, u16* __restrict__ dst)
{
  int i = blockIdx.x * 256 + threadIdx.x;  // 524288
  int r = i & 63, e = (i >> 6) & 7, d = i >> 9;
  dst[i] = f2bf(up_w[(e * 1024 + d) * 64 + r]);
}

// --------------------------- gating ----------------------------------------
__global__ __launch_bounds__(256) void gate_k(const float* __restrict__ x1,
                                              const float* __restrict__ wg,
                                              float* __restrict__ gates)
{
  const int wv = threadIdx.x >> 6, lane = threadIdx.x & 63;
  const int b = blockIdx.x * 4 + wv;
  const float* xp = x1 + (long)b * 1024;
  float lg[8];
  #pragma unroll
  for (int e = 0; e < 8; e++) lg[e] = 0.f;
  for (int i = 0; i < 16; i++) {
    int d = i * 64 + lane;
    float xv = xp[d];
    #pragma unroll
    for (int e = 0; e < 8; e++) lg[e] += xv * wg[d * 8 + e];
  }
  #pragma unroll
  for (int e = 0; e < 8; e++)
    #pragma unroll
    for (int off = 32; off >= 1; off >>= 1) lg[e] += __shfl_xor(lg[e], off);
  if (lane == 0) {
    int e1 = 0; float v1 = lg[0];
    #pragma unroll
    for (int e = 1; e < 8; e++) if (lg[e] > v1) { v1 = lg[e]; e1 = e; }
    int e2 = -1; float v2 = -1e30f;
    #pragma unroll
    for (int e = 0; e < 8; e++) if (e != e1 && lg[e] > v2) { v2 = lg[e]; e2 = e; }
    float ex = __expf(v2 - v1);
    float inv = 1.f / (1.f + ex);
    #pragma unroll
    for (int e = 0; e < 8; e++)
      gates[b * 8 + e] = (e == e1) ? inv : ((e == e2) ? ex * inv : 0.f);
  }
}

__global__ void moe_loss_k(const float* __restrict__ gates, float* __restrict__ out)
{
  if (threadIdx.x != 0) return;
  float imp[8], ld[8];
  for (int e = 0; e < 8; e++) { imp[e] = 0.f; ld[e] = 0.f; }
  for (int b = 0; b < 64; b++)
    for (int e = 0; e < 8; e++) {
      float g = gates[b * 8 + e];
      imp[e] += g;
      if (g > 0.f) ld[e] += 1.f;
    }
  float mi = 0.f, ml = 0.f;
  for (int e = 0; e < 8; e++) { mi += imp[e]; ml += ld[e]; }
  mi *= 0.125f; ml *= 0.125f;
  float vi = 0.f, vl = 0.f;
  for (int e = 0; e < 8; e++) {
    float a = imp[e] - mi; vi += a * a;
    float c = ld[e] - ml; vl += c * c;
  }
  vi *= (1.f / 7.f); vl *= (1.f / 7.f);
  out[0] = 0.01f * (vi / (mi * mi + 1e-10f) + vl / (ml * ml + 1e-10f));
}

// gb[b][d] = sum_e gates[b,e] * up_b[e,d]
__global__ __launch_bounds__(256) void gb_k(const float* __restrict__ gates,
                                            const float* __restrict__ up_b,
                                            float* __restrict__ gb)
{
  int b = blockIdx.x, d0 = threadIdx.x * 4;
  float g[8];
  #pragma unroll
  for (int e = 0; e < 8; e++) g[e] = gates[b * 8 + e];
  float s0 = 0, s1 = 0, s2 = 0, s3 = 0;
  #pragma unroll
  for (int e = 0; e < 8; e++) {
    float4 u = *(const float4*)(up_b + e * 1024 + d0);
    s0 += g[e] * u.x; s1 += g[e] * u.y; s2 += g[e] * u.z; s3 += g[e] * u.w;
  }
  float4 r; r.x = s0; r.y = s1; r.z = s2; r.w = s3;
  *(float4*)(gb + b * 1024 + d0) = r;
}

// ---------------------------------------------------------------------------
extern "C" void kernel_launch(void* const* d_in, const int* in_sizes, int n_in,
                              void* d_out, int out_size, void* d_ws, size_t ws_size,
                              hipStream_t stream)
{
  (void)in_sizes; (void)n_in; (void)out_size; (void)ws_size;
  const float* x      = (const float*)d_in[0];
  const float* ln1_w  = (const float*)d_in[1];
  const float* ln1_b  = (const float*)d_in[2];
  const float* in_w   = (const float*)d_in[3];
  const float* in_b   = (const float*)d_in[4];
  const float* out_w  = (const float*)d_in[5];
  const float* out_b  = (const float*)d_in[6];
  const float* ln2_w  = (const float*)d_in[7];
  const float* ln2_b  = (const float*)d_in[8];
  const float* fc_w   = (const float*)d_in[9];
  const float* fc_b   = (const float*)d_in[10];
  const float* pj_w   = (const float*)d_in[11];
  const float* pj_b   = (const float*)d_in[12];
  const float* w_gate = (const float*)d_in[13];
  const float* down_w = (const float*)d_in[14];
  const float* down_b = (const float*)d_in[15];
  const float* up_w   = (const float*)d_in[16];
  const float* up_b   = (const float*)d_in[17];
  float* out = (float*)d_out;
  char* ws = (char*)d_ws;

  // ws layout (total 119,932,928 B ~ 114.4 MB), lifetime-aliased
  u16* wb_in   = (u16*)(ws + 0);          // 6 MB   (dead after qkv gemm)
  u16* wb_out  = (u16*)(ws + 6291456);    // 2 MB   (dead after out_proj)
  u16* wb_down = (u16*)(ws + 8388608);    // 1 MB   (dead after down gemm)
  u16* wb_up   = (u16*)(ws + 9437184);    // 1 MB   (dead after up gemm)
  u16* wb_fc   = (u16*)(ws + 0);          // 8 MB   (aliases in/out, converted late)
  u16* wb_pj   = (u16*)(ws + 10485760);   // 8 MB
  float* muv   = (float*)(ws + 18874368); // 64 KB
  float* rsv   = (float*)(ws + 18939904); // 64 KB
  float* gates = (float*)(ws + 19005440); // 2 KB
  float* gb    = (float*)(ws + 19007488); // 256 KB
  u16* qkv     = (u16*)(ws + 19269632);   // 96 MB  (dead after out_proj)
  u16* xln2    = (u16*)(ws + 19269632);   // 32 MB  (alias qkv[0:32M])
  u16* hg      = (u16*)(ws + 52824064);   // 16 MB  (alias qkv[32M:48M])
  u16* h2c     = (u16*)(ws + 69601280);   // 32 MB  (alias qkv[48M:80M])

  // LN1 stats + phase-1 weight converts
  stats_k<<<4096, 256, 0, stream>>>(x, muv, rsv);
  cvtk<<<3072, 256, 0, stream>>>(in_w, wb_in, 786432);
  cvtk<<<1024, 256, 0, stream>>>(out_w, wb_out, 262144);
  cvtk<<<512, 256, 0, stream>>>(down_w, wb_down, 131072);
  wupk<<<2048, 256, 0, stream>>>(up_w, wb_up);

  // qkv = LN1(x) @ in_w^T + in_b   (LN fused into A-staging)
  gemm_k<0, 1><<<dim3(24, 128), 256, 0, stream>>>(
      x, 1024, wb_in, 1024, in_b, nullptr, muv, rsv, ln1_w, ln1_b,
      nullptr, qkv, 3072, 1024);

  // fused attention; O overwrites q-slot of qkv
  attn_k<<<1024, 256, 0, stream>>>(qkv);

  // x1 = O @ out_w^T + out_b + x  -> d_out (f32)
  gemm_k<1, 0><<<dim3(8, 128), 256, 0, stream>>>(
      qkv, 3072, wb_out, 1024, out_b, x, nullptr, nullptr, nullptr, nullptr,
      out, nullptr, 1024, 1024);

  // gating on x1 rows 0..63 (token 0 of each sequence)
  gate_k<<<16, 256, 0, stream>>>(out, w_gate, gates);
  moe_loss_k<<<1, 64, 0, stream>>>(gates, out + 16777216);
  gb_k<<<64, 256, 0, stream>>>(gates, up_b, gb);

  // LN2 must see pure x1 (before y accumulates into d_out)
  ln_k<<<4096, 256, 0, stream>>>(out, ln2_w, ln2_b, xln2);

  // adapter: down (relu, *gate) from f32 x1; up accumulates y into d_out
  gemm_k<2, 2><<<dim3(4, 128), 256, 0, stream>>>(
      out, 1024, wb_down, 1024, down_b, gates, nullptr, nullptr, nullptr, nullptr,
      nullptr, hg, 512, 1024);
  gemm_k<3, 0><<<dim3(8, 128), 256, 0, stream>>>(
      hg, 512, wb_up, 512, nullptr, gb, nullptr, nullptr, nullptr, nullptr,
      out, nullptr, 1024, 512);

  // phase-2 weight converts (overwrite dead phase-1 buffers)
  cvtk<<<4096, 256, 0, stream>>>(fc_w, wb_fc, 1048576);
  cvtk<<<4096, 256, 0, stream>>>(pj_w, wb_pj, 1048576);

  // MLP in 4 K-chunks: h2c = QuickGELU(xln2 @ fc_w_c^T + b_c); out += h2c @ pj_w_c^T
  for (int c = 0; c < 4; c++) {
    gemm_k<4, 0><<<dim3(8, 128), 256, 0, stream>>>(
        xln2, 1024, wb_fc + (long)c * 1048576, 1024, fc_b + c * 1024,
        nullptr, nullptr, nullptr, nullptr, nullptr, nullptr, h2c, 1024, 1024);
    gemm_k<5, 0><<<dim3(8, 128), 256, 0, stream>>>(
        h2c, 1024, wb_pj + c * 1024, 4096, (c == 0) ? pj_b : nullptr,
        nullptr, nullptr, nullptr, nullptr, nullptr, out, nullptr, 1024, 1024);
  }
}

// Round 3
// 1172.102 us; speedup vs baseline: 1.1602x; 1.1602x over previous
//
#include <hip/hip_runtime.h>

typedef unsigned short u16;
typedef unsigned int u32;
typedef __bf16 bf16x8 __attribute__((ext_vector_type(8)));
typedef float f32x4 __attribute__((ext_vector_type(4)));

#define MFMA16(a, b, c) __builtin_amdgcn_mfma_f32_16x16x32_bf16(a, b, c, 0, 0, 0)

__device__ __forceinline__ u16 f2bf(float f) {
  u32 u = __builtin_bit_cast(u32, f);
  u32 r = u + 0x7fffu + ((u >> 16) & 1u);
  return (u16)(r >> 16);
}

__device__ __forceinline__ uint4 cvt8(const float4& a, const float4& b) {
  union { u16 h[8]; uint4 q; } u;
  u.h[0] = f2bf(a.x); u.h[1] = f2bf(a.y); u.h[2] = f2bf(a.z); u.h[3] = f2bf(a.w);
  u.h[4] = f2bf(b.x); u.h[5] = f2bf(b.y); u.h[6] = f2bf(b.z); u.h[7] = f2bf(b.w);
  return u.q;
}

// async global->LDS, 16B per lane; lds dst is wave-uniform base + lane*16
__device__ __forceinline__ void gload16(const u16* g, u16* l) {
  __builtin_amdgcn_global_load_lds(
      (const __attribute__((address_space(1))) u32*)g,
      (__attribute__((address_space(3))) u32*)l, 16, 0, 0);
}

// ---------------------------------------------------------------------------
// 128x128-tile bf16 MFMA GEMM, BK=32, m97-style global_load_lds staging.
// C = A(MxK, lda) * W(NxK, ldb)^T, fused epilogues.
// ASRC 0: A bf16 (async staging);  2: A f32 convert-in-staging (adapter down)
// MODE 0: +bias, store bf16               (qkv)
// MODE 1: +bias +aux0(x f32), store f32   (out_proj -> x1 in d_out)
// MODE 2: +bias, relu, *gates, bf16       (adapter down -> hg)
// MODE 3: outF += 0.1*(acc + gb)          (adapter up -> y into d_out)
// MODE 4: +bias, QuickGELU, bf16          (c_fc -> h2)
// MODE 5: outF += acc (+bias if given)    (c_proj into d_out)
// ---------------------------------------------------------------------------
template <int MODE, int ASRC>
__global__ __launch_bounds__(256) void gemm_k(
    const void* __restrict__ Av, int lda,
    const u16* __restrict__ W, int ldb,
    const float* __restrict__ bias, const float* __restrict__ aux0,
    float* __restrict__ outF, u16* __restrict__ outB, int N, int K)
{
  __shared__ u16 As[128 * 32];
  __shared__ u16 Bs[128 * 32];
  const int tid = threadIdx.x;
  const int m0 = blockIdx.y * 128, n0 = blockIdx.x * 128;
  const int w = tid >> 6, lane = tid & 63, lr = lane & 15, quad = lane >> 4;
  const int wm = (w >> 1) * 64, wn = (w & 1) * 64;

  f32x4 acc[4][4];
  #pragma unroll
  for (int i = 0; i < 4; i++)
    #pragma unroll
    for (int j = 0; j < 4; j++)
      #pragma unroll
      for (int r = 0; r < 4; r++) acc[i][j][r] = 0.f;

  // async-staging source addressing: wave w, issue t covers tile rows
  // [(w*2+t)*16, +16); lane L -> row +(L>>2), elem col (L&3)*8
  const int srow = w * 32 + (lane >> 2);
  const int scol = (lane & 3) * 8;
  const u16* gB0 = W + (long)(n0 + srow) * ldb + scol;
  const u16* gB1 = gB0 + (long)16 * ldb;
  u16* lB0 = Bs + w * 1024;
  u16* lB1 = lB0 + 512;

  const u16* gA0 = nullptr; const u16* gA1 = nullptr;
  u16* lA0 = As + w * 1024; u16* lA1 = lA0 + 512;
  const float* F1 = nullptr; const float* F2 = nullptr;
  const int r0 = tid >> 2, ch0 = (tid & 3) * 8;
  if constexpr (ASRC == 0) {
    gA0 = (const u16*)Av + (long)(m0 + srow) * lda + scol;
    gA1 = gA0 + (long)16 * lda;
  } else {
    F1 = (const float*)Av + (long)(m0 + r0) * lda + ch0;
    F2 = (const float*)Av + (long)(m0 + r0 + 64) * lda + ch0;
  }

  for (int k0 = 0; k0 < K; k0 += 32) {
    if constexpr (ASRC == 0) {
      gload16(gA0 + k0, lA0);
      gload16(gA1 + k0, lA1);
      gload16(gB0 + k0, lB0);
      gload16(gB1 + k0, lB1);
      __syncthreads();
    } else {
      float4 p0 = *(const float4*)(F1 + k0);
      float4 p1 = *(const float4*)(F1 + k0 + 4);
      float4 q0 = *(const float4*)(F2 + k0);
      float4 q1 = *(const float4*)(F2 + k0 + 4);
      __syncthreads();  // everyone done with previous tile
      gload16(gB0 + k0, lB0);
      gload16(gB1 + k0, lB1);
      *(uint4*)&As[r0 * 32 + ch0] = cvt8(p0, p1);
      *(uint4*)&As[(r0 + 64) * 32 + ch0] = cvt8(q0, q1);
      __syncthreads();
    }
    bf16x8 bfr[4];
    #pragma unroll
    for (int j = 0; j < 4; j++)
      bfr[j] = *(const bf16x8*)&Bs[(wn + j * 16 + lr) * 32 + quad * 8];
    #pragma unroll
    for (int i = 0; i < 4; i++) {
      bf16x8 af = *(const bf16x8*)&As[(wm + i * 16 + lr) * 32 + quad * 8];
      #pragma unroll
      for (int j = 0; j < 4; j++)
        acc[i][j] = MFMA16(af, bfr[j], acc[i][j]);
    }
    __syncthreads();
  }

  #pragma unroll
  for (int i = 0; i < 4; i++) {
    #pragma unroll
    for (int j = 0; j < 4; j++) {
      #pragma unroll
      for (int r = 0; r < 4; r++) {
        const int gm = m0 + wm + i * 16 + quad * 4 + r;
        const int gn = n0 + wn + j * 16 + lr;
        const long oidx = (long)gm * N + gn;
        float v = acc[i][j][r];
        if constexpr (MODE == 0) {
          v += bias[gn];
          outB[oidx] = f2bf(v);
        } else if constexpr (MODE == 1) {
          v += bias[gn] + aux0[oidx];
          outF[oidx] = v;
        } else if constexpr (MODE == 2) {
          v += bias[gn];
          v = fmaxf(v, 0.f);
          float g = aux0[(gm & 63) * 8 + (gn >> 6)];
          outB[oidx] = f2bf(v * g);
        } else if constexpr (MODE == 3) {
          outF[oidx] += 0.1f * (v + aux0[(gm & 63) * 1024 + gn]);
        } else if constexpr (MODE == 4) {
          v += bias[gn];
          v = v / (1.f + __expf(-1.702f * v));
          outB[oidx] = f2bf(v);
        } else {
          if (bias) v += bias[gn];
          outF[oidx] += v;
        }
      }
    }
  }
}

// ---------------------------------------------------------------------------
// Fused attention per (b,h): S=QK^T/8 -> softmax -> P*V; O overwrites q-slot.
// qkv: [tok=l*64+b][3072], q@+0, k@+1024, v@+2048, col h*64+d. LDS ~51KB.
// ---------------------------------------------------------------------------
__global__ __launch_bounds__(256) void attn_k(u16* __restrict__ qkv)
{
  __shared__ u16 Vt[64 * 264];
  __shared__ u16 Ps[32 * 264];
  __shared__ float rowstat[64];
  float* red = (float*)Ps;  // red's lifetime ends before Ps is written
  const int bh = blockIdx.x, b = bh >> 4, h = bh & 15;
  const int tid = threadIdx.x, w = tid >> 6, lane = tid & 63;
  const int lr = lane & 15, quad = lane >> 4;
  const long base = (long)b * 3072 + h * 64;

  for (int c = tid; c < 2048; c += 256) {
    int m = c >> 3, ch = (c & 7) * 8;
    uint4 vv = *(const uint4*)(qkv + (long)m * 196608 + base + 2048 + ch);
    const u16* s = (const u16*)&vv;
    #pragma unroll
    for (int t = 0; t < 8; t++) Vt[(ch + t) * 264 + m] = s[t];
  }
  __syncthreads();

  for (int qb = 0; qb < 4; qb++) {
    f32x4 acc[4][4];
    #pragma unroll
    for (int i = 0; i < 4; i++)
      #pragma unroll
      for (int j = 0; j < 4; j++)
        #pragma unroll
        for (int r = 0; r < 4; r++) acc[i][j][r] = 0.f;

    #pragma unroll
    for (int ks = 0; ks < 2; ks++) {
      bf16x8 bfr[4];
      #pragma unroll
      for (int j = 0; j < 4; j++) {
        int key = w * 64 + j * 16 + lr;
        bfr[j] = *(const bf16x8*)(qkv + (long)key * 196608 + base + 1024 + ks * 32 + quad * 8);
      }
      #pragma unroll
      for (int i = 0; i < 4; i++) {
        int gq = qb * 64 + i * 16 + lr;
        bf16x8 af = *(const bf16x8*)(qkv + (long)gq * 196608 + base + ks * 32 + quad * 8);
        #pragma unroll
        for (int j = 0; j < 4; j++)
          acc[i][j] = MFMA16(af, bfr[j], acc[i][j]);
      }
    }

    #pragma unroll
    for (int i = 0; i < 4; i++) {
      #pragma unroll
      for (int r = 0; r < 4; r++) {
        float m = -1e30f;
        #pragma unroll
        for (int j = 0; j < 4; j++) {
          float s = acc[i][j][r] * 0.125f;
          acc[i][j][r] = s;
          m = fmaxf(m, s);
        }
        #pragma unroll
        for (int off = 1; off < 16; off <<= 1) m = fmaxf(m, __shfl_xor(m, off));
        if (lr == 0) red[w * 64 + i * 16 + quad * 4 + r] = m;
      }
    }
    __syncthreads();
    if (tid < 64)
      rowstat[tid] = fmaxf(fmaxf(red[tid], red[64 + tid]),
                           fmaxf(red[128 + tid], red[192 + tid]));
    __syncthreads();

    #pragma unroll
    for (int i = 0; i < 4; i++) {
      #pragma unroll
      for (int r = 0; r < 4; r++) {
        float rm = rowstat[i * 16 + quad * 4 + r];
        float s = 0.f;
        #pragma unroll
        for (int j = 0; j < 4; j++) {
          float e = __expf(acc[i][j][r] - rm);
          acc[i][j][r] = e;
          s += e;
        }
        #pragma unroll
        for (int off = 1; off < 16; off <<= 1) s += __shfl_xor(s, off);
        if (lr == 0) red[w * 64 + i * 16 + quad * 4 + r] = s;
      }
    }
    __syncthreads();
    if (tid < 64)
      rowstat[tid] = red[tid] + red[64 + tid] + red[128 + tid] + red[192 + tid];
    __syncthreads();

    #pragma unroll
    for (int hf = 0; hf < 2; hf++) {
      #pragma unroll
      for (int ii = 0; ii < 2; ii++) {
        int i = hf * 2 + ii;
        #pragma unroll
        for (int r = 0; r < 4; r++) {
          int row = i * 16 + quad * 4 + r;
          float inv = 1.f / rowstat[row];
          #pragma unroll
          for (int j = 0; j < 4; j++)
            Ps[(row - hf * 32) * 264 + w * 64 + j * 16 + lr] =
                f2bf(acc[i][j][r] * inv);
        }
      }
      __syncthreads();
      f32x4 o[2];
      #pragma unroll
      for (int j2 = 0; j2 < 2; j2++)
        #pragma unroll
        for (int r = 0; r < 4; r++) o[j2][r] = 0.f;
      #pragma unroll
      for (int ks = 0; ks < 8; ks++) {
        bf16x8 af = *(const bf16x8*)&Ps[((w >> 1) * 16 + lr) * 264 + ks * 32 + quad * 8];
        #pragma unroll
        for (int j2 = 0; j2 < 2; j2++) {
          int j = (w & 1) * 2 + j2;
          bf16x8 bv = *(const bf16x8*)&Vt[(j * 16 + lr) * 264 + ks * 32 + quad * 8];
          o[j2] = MFMA16(af, bv, o[j2]);
        }
      }
      int l0 = qb * 64 + hf * 32 + (w >> 1) * 16 + quad * 4;
      #pragma unroll
      for (int j2 = 0; j2 < 2; j2++) {
        int j = (w & 1) * 2 + j2;
        #pragma unroll
        for (int r = 0; r < 4; r++)
          qkv[(long)(l0 + r) * 196608 + base + j * 16 + lr] = f2bf(o[j2][r]);
      }
      __syncthreads();
    }
  }
}

// --------------------------- LayerNorm (f32 -> bf16) -----------------------
__global__ __launch_bounds__(256) void ln_k(const float* __restrict__ x,
                                            const float* __restrict__ wt,
                                            const float* __restrict__ bs,
                                            u16* __restrict__ out)
{
  const int tok = blockIdx.x * 4 + (threadIdx.x >> 6);
  const int lane = threadIdx.x & 63;
  const float* xp = x + (long)tok * 1024;
  float4 v[4];
  float s = 0.f, s2 = 0.f;
  #pragma unroll
  for (int t = 0; t < 4; t++) {
    v[t] = *(const float4*)(xp + t * 256 + lane * 4);
    s += v[t].x + v[t].y + v[t].z + v[t].w;
    s2 += v[t].x * v[t].x + v[t].y * v[t].y + v[t].z * v[t].z + v[t].w * v[t].w;
  }
  #pragma unroll
  for (int off = 32; off >= 1; off >>= 1) {
    s += __shfl_xor(s, off);
    s2 += __shfl_xor(s2, off);
  }
  const float m = s * (1.f / 1024.f);
  const float rstd = rsqrtf(s2 * (1.f / 1024.f) - m * m + 1e-5f);
  u16* op = out + (long)tok * 1024;
  #pragma unroll
  for (int t = 0; t < 4; t++) {
    int d = t * 256 + lane * 4;
    float4 wv = *(const float4*)(wt + d);
    float4 bv = *(const float4*)(bs + d);
    union { u16 h[4]; uint2 q; } o;
    o.h[0] = f2bf((v[t].x - m) * rstd * wv.x + bv.x);
    o.h[1] = f2bf((v[t].y - m) * rstd * wv.y + bv.y);
    o.h[2] = f2bf((v[t].z - m) * rstd * wv.z + bv.z);
    o.h[3] = f2bf((v[t].w - m) * rstd * wv.w + bv.w);
    *(uint2*)(op + d) = o.q;
  }
}

// --------------------------- weight converts -------------------------------
__global__ void cvtk(const float* __restrict__ src, u16* __restrict__ dst, int n4)
{
  int i = blockIdx.x * 256 + threadIdx.x;
  if (i >= n4) return;
  float4 v = ((const float4*)src)[i];
  union { u16 h[4]; uint2 q; } o;
  o.h[0] = f2bf(v.x); o.h[1] = f2bf(v.y); o.h[2] = f2bf(v.z); o.h[3] = f2bf(v.w);
  ((uint2*)dst)[i] = o.q;
}

// dst[d*512 + e*64 + r] = up_w[(e*1024 + d)*64 + r]   (up_w is (E,D,R))
__global__ void wupk(const float* __restrict__ up_w, u16* __restrict__ dst)
{
  int i = blockIdx.x * 256 + threadIdx.x;  // 524288
  int r = i & 63, e = (i >> 6) & 7, d = i >> 9;
  dst[i] = f2bf(up_w[(e * 1024 + d) * 64 + r]);
}

// --------------------------- gating ----------------------------------------
__global__ __launch_bounds__(256) void gate_k(const float* __restrict__ x1,
                                              const float* __restrict__ wg,
                                              float* __restrict__ gates)
{
  const int wv = threadIdx.x >> 6, lane = threadIdx.x & 63;
  const int b = blockIdx.x * 4 + wv;
  const float* xp = x1 + (long)b * 1024;
  float lg[8];
  #pragma unroll
  for (int e = 0; e < 8; e++) lg[e] = 0.f;
  for (int i = 0; i < 16; i++) {
    int d = i * 64 + lane;
    float xv = xp[d];
    #pragma unroll
    for (int e = 0; e < 8; e++) lg[e] += xv * wg[d * 8 + e];
  }
  #pragma unroll
  for (int e = 0; e < 8; e++)
    #pragma unroll
    for (int off = 32; off >= 1; off >>= 1) lg[e] += __shfl_xor(lg[e], off);
  if (lane == 0) {
    int e1 = 0; float v1 = lg[0];
    #pragma unroll
    for (int e = 1; e < 8; e++) if (lg[e] > v1) { v1 = lg[e]; e1 = e; }
    int e2 = -1; float v2 = -1e30f;
    #pragma unroll
    for (int e = 0; e < 8; e++) if (e != e1 && lg[e] > v2) { v2 = lg[e]; e2 = e; }
    float ex = __expf(v2 - v1);
    float inv = 1.f / (1.f + ex);
    #pragma unroll
    for (int e = 0; e < 8; e++)
      gates[b * 8 + e] = (e == e1) ? inv : ((e == e2) ? ex * inv : 0.f);
  }
}

__global__ void moe_loss_k(const float* __restrict__ gates, float* __restrict__ out)
{
  if (threadIdx.x != 0) return;
  float imp[8], ld[8];
  for (int e = 0; e < 8; e++) { imp[e] = 0.f; ld[e] = 0.f; }
  for (int b = 0; b < 64; b++)
    for (int e = 0; e < 8; e++) {
      float g = gates[b * 8 + e];
      imp[e] += g;
      if (g > 0.f) ld[e] += 1.f;
    }
  float mi = 0.f, ml = 0.f;
  for (int e = 0; e < 8; e++) { mi += imp[e]; ml += ld[e]; }
  mi *= 0.125f; ml *= 0.125f;
  float vi = 0.f, vl = 0.f;
  for (int e = 0; e < 8; e++) {
    float a = imp[e] - mi; vi += a * a;
    float c = ld[e] - ml; vl += c * c;
  }
  vi *= (1.f / 7.f); vl *= (1.f / 7.f);
  out[0] = 0.01f * (vi / (mi * mi + 1e-10f) + vl / (ml * ml + 1e-10f));
}

// gb[b][d] = sum_e gates[b,e] * up_b[e,d]
__global__ __launch_bounds__(256) void gb_k(const float* __restrict__ gates,
                                            const float* __restrict__ up_b,
                                            float* __restrict__ gb)
{
  int b = blockIdx.x, d0 = threadIdx.x * 4;
  float g[8];
  #pragma unroll
  for (int e = 0; e < 8; e++) g[e] = gates[b * 8 + e];
  float s0 = 0, s1 = 0, s2 = 0, s3 = 0;
  #pragma unroll
  for (int e = 0; e < 8; e++) {
    float4 u = *(const float4*)(up_b + e * 1024 + d0);
    s0 += g[e] * u.x; s1 += g[e] * u.y; s2 += g[e] * u.z; s3 += g[e] * u.w;
  }
  float4 r; r.x = s0; r.y = s1; r.z = s2; r.w = s3;
  *(float4*)(gb + b * 1024 + d0) = r;
}

// ---------------------------------------------------------------------------
extern "C" void kernel_launch(void* const* d_in, const int* in_sizes, int n_in,
                              void* d_out, int out_size, void* d_ws, size_t ws_size,
                              hipStream_t stream)
{
  (void)in_sizes; (void)n_in; (void)out_size;
  const float* x      = (const float*)d_in[0];
  const float* ln1_w  = (const float*)d_in[1];
  const float* ln1_b  = (const float*)d_in[2];
  const float* in_w   = (const float*)d_in[3];
  const float* in_b   = (const float*)d_in[4];
  const float* out_w  = (const float*)d_in[5];
  const float* out_b  = (const float*)d_in[6];
  const float* ln2_w  = (const float*)d_in[7];
  const float* ln2_b  = (const float*)d_in[8];
  const float* fc_w   = (const float*)d_in[9];
  const float* fc_b   = (const float*)d_in[10];
  const float* pj_w   = (const float*)d_in[11];
  const float* pj_b   = (const float*)d_in[12];
  const float* w_gate = (const float*)d_in[13];
  const float* down_w = (const float*)d_in[14];
  const float* down_b = (const float*)d_in[15];
  const float* up_w   = (const float*)d_in[16];
  const float* up_b   = (const float*)d_in[17];
  float* out = (float*)d_out;
  char* ws = (char*)d_ws;

  // ws layout (base footprint ~115 MB, proven in round 2), lifetime-aliased
  u16* wb_in   = (u16*)(ws + 0);          // 6 MB   (dead after qkv gemm)
  u16* wb_out  = (u16*)(ws + 6291456);    // 2 MB   (dead after out_proj)
  u16* wb_down = (u16*)(ws + 8388608);    // 1 MB
  u16* wb_up   = (u16*)(ws + 9437184);    // 1 MB
  u16* wb_fc   = (u16*)(ws + 0);          // 8 MB   (aliases in/out, converted late)
  u16* wb_pj   = (u16*)(ws + 10485760);   // 8 MB
  float* gates = (float*)(ws + 19005440); // 2 KB
  float* gb    = (float*)(ws + 19007488); // 256 KB
  u16* qkv     = (u16*)(ws + 19269632);   // 96 MB  (dead after out_proj)
  u16* xln2    = (u16*)(ws + 19269632);   // 32 MB  (alias qkv[0:32M])
  u16* hg      = (u16*)(ws + 52824064);   // 16 MB  (alias qkv[32M:48M])
  u16* h2      = (u16*)(ws + 69601280);   // 32 MB chunked / 128 MB if ws allows
  // xln (LN1 output, bf16) lives in d_out until out_proj overwrites it
  u16* xln = (u16*)d_out;

  const bool big = ws_size >= (size_t)203819008;  // 69601280 + 128 MB

  // phase-1 weight converts
  cvtk<<<3072, 256, 0, stream>>>(in_w, wb_in, 786432);
  cvtk<<<1024, 256, 0, stream>>>(out_w, wb_out, 262144);
  cvtk<<<512, 256, 0, stream>>>(down_w, wb_down, 131072);
  wupk<<<2048, 256, 0, stream>>>(up_w, wb_up);

  // LN1 -> xln (bf16, in d_out); qkv = xln @ in_w^T + in_b
  ln_k<<<4096, 256, 0, stream>>>(x, ln1_w, ln1_b, xln);
  gemm_k<0, 0><<<dim3(24, 128), 256, 0, stream>>>(
      xln, 1024, wb_in, 1024, in_b, nullptr, nullptr, qkv, 3072, 1024);

  // fused attention; O overwrites q-slot of qkv
  attn_k<<<1024, 256, 0, stream>>>(qkv);

  // x1 = O @ out_w^T + out_b + x  -> d_out (f32)
  gemm_k<1, 0><<<dim3(8, 128), 256, 0, stream>>>(
      qkv, 3072, wb_out, 1024, out_b, x, out, nullptr, 1024, 1024);

  // gating on x1 rows 0..63 (token 0 of each sequence)
  gate_k<<<16, 256, 0, stream>>>(out, w_gate, gates);
  moe_loss_k<<<1, 64, 0, stream>>>(gates, out + 16777216);
  gb_k<<<64, 256, 0, stream>>>(gates, up_b, gb);

  // LN2 must see pure x1 (before y accumulates into d_out)
  ln_k<<<4096, 256, 0, stream>>>(out, ln2_w, ln2_b, xln2);

  // adapter: down (relu, *gate) from f32 x1; up accumulates y into d_out
  gemm_k<2, 2><<<dim3(4, 128), 256, 0, stream>>>(
      out, 1024, wb_down, 1024, down_b, gates, nullptr, hg, 512, 1024);
  gemm_k<3, 0><<<dim3(8, 128), 256, 0, stream>>>(
      hg, 512, wb_up, 512, nullptr, gb, out, nullptr, 1024, 512);

  // phase-2 weight converts (overwrite dead phase-1 buffers)
  cvtk<<<4096, 256, 0, stream>>>(fc_w, wb_fc, 1048576);
  cvtk<<<4096, 256, 0, stream>>>(pj_w, wb_pj, 1048576);

  if (big) {
    // single-shot MLP: h2 = QuickGELU(xln2 @ fc_w^T + fc_b); out += h2 @ pj_w^T + pj_b
    gemm_k<4, 0><<<dim3(32, 128), 256, 0, stream>>>(
        xln2, 1024, wb_fc, 1024, fc_b, nullptr, nullptr, h2, 4096, 1024);
    gemm_k<5, 0><<<dim3(8, 128), 256, 0, stream>>>(
        h2, 4096, wb_pj, 4096, pj_b, nullptr, out, nullptr, 1024, 4096);
  } else {
    // 4 K-chunks (proven 115 MB footprint)
    for (int c = 0; c < 4; c++) {
      gemm_k<4, 0><<<dim3(8, 128), 256, 0, stream>>>(
          xln2, 1024, wb_fc + (long)c * 1048576, 1024, fc_b + c * 1024,
          nullptr, nullptr, h2, 1024, 1024);
      gemm_k<5, 0><<<dim3(8, 128), 256, 0, stream>>>(
          h2, 1024, wb_pj + c * 1024, 4096, (c == 0) ? pj_b : nullptr,
          nullptr, out, nullptr, 1024, 1024);
    }
  }
}

// Round 4
// 1109.058 us; speedup vs baseline: 1.2261x; 1.0568x over previous
//
#include <hip/hip_runtime.h>

typedef unsigned short u16;
typedef unsigned int u32;
typedef __bf16 bf16x8 __attribute__((ext_vector_type(8)));
typedef float f32x4 __attribute__((ext_vector_type(4)));

#define MFMA16(a, b, c) __builtin_amdgcn_mfma_f32_16x16x32_bf16(a, b, c, 0, 0, 0)

__device__ __forceinline__ u16 f2bf(float f) {
  u32 u = __builtin_bit_cast(u32, f);
  u32 r = u + 0x7fffu + ((u >> 16) & 1u);
  return (u16)(r >> 16);
}

__device__ __forceinline__ uint4 cvt8(const float4& a, const float4& b) {
  union { u16 h[8]; uint4 q; } u;
  u.h[0] = f2bf(a.x); u.h[1] = f2bf(a.y); u.h[2] = f2bf(a.z); u.h[3] = f2bf(a.w);
  u.h[4] = f2bf(b.x); u.h[5] = f2bf(b.y); u.h[6] = f2bf(b.z); u.h[7] = f2bf(b.w);
  return u.q;
}

// async global->LDS, 16B per lane; lds dst is wave-uniform base + lane*16
__device__ __forceinline__ void gload16(const u16* g, u16* l) {
  __builtin_amdgcn_global_load_lds(
      (const __attribute__((address_space(1))) u32*)g,
      (__attribute__((address_space(3))) u32*)l, 16, 0, 0);
}

// ---------------------------------------------------------------------------
// 128x128-tile bf16 MFMA GEMM, BK=32, global_load_lds staging, 1-D swizzled
// grid: groups of 32 M-blocks x all N-blocks for L2 locality (per-XCD working
// set ~1MB A + ~1MB B << 4MB L2). M fixed at 16384 (128 M-blocks).
// C = A(MxK, lda) * W(NxK, ldb)^T, fused epilogues.
// ASRC 0: A bf16 (async);  2: A f32 convert-in-staging (adapter down)
// MODE 0: +bias, store bf16               (qkv)
// MODE 1: +bias +aux0(x f32), store f32   (out_proj -> x1 in d_out)
// MODE 2: +bias, relu, *gates, bf16       (adapter down -> hg)
// MODE 3: outF += 0.1*(acc + gb)          (adapter up -> y into d_out)
// MODE 4: +bias, QuickGELU, bf16          (c_fc -> h2)
// MODE 5: outF += acc (+bias if given)    (c_proj into d_out)
// ---------------------------------------------------------------------------
template <int MODE, int ASRC>
__global__ __launch_bounds__(256) void gemm_k(
    const void* __restrict__ Av, int lda,
    const u16* __restrict__ W, int ldb,
    const float* __restrict__ bias, const float* __restrict__ aux0,
    float* __restrict__ outF, u16* __restrict__ outB, int N, int K)
{
  __shared__ u16 As[128 * 32];
  __shared__ u16 Bs[128 * 32];
  const int tid = threadIdx.x;
  // swizzle: group g spans 32 consecutive M-blocks x all nxb N-blocks
  const int nxb = gridDim.x >> 7;         // N / 128
  const int gsz = nxb << 5;               // 32 * nxb
  const int g = blockIdx.x / gsz;
  const int rem = blockIdx.x - g * gsz;
  const int m0 = ((g << 5) + (rem & 31)) * 128;
  const int n0 = (rem >> 5) * 128;
  const int w = tid >> 6, lane = tid & 63, lr = lane & 15, quad = lane >> 4;
  const int wm = (w >> 1) * 64, wn = (w & 1) * 64;

  f32x4 acc[4][4];
  #pragma unroll
  for (int i = 0; i < 4; i++)
    #pragma unroll
    for (int j = 0; j < 4; j++)
      #pragma unroll
      for (int r = 0; r < 4; r++) acc[i][j][r] = 0.f;

  const int srow = w * 32 + (lane >> 2);
  const int scol = (lane & 3) * 8;
  const u16* gB0 = W + (long)(n0 + srow) * ldb + scol;
  const u16* gB1 = gB0 + (long)16 * ldb;
  u16* lB0 = Bs + w * 1024;
  u16* lB1 = lB0 + 512;

  const u16* gA0 = nullptr; const u16* gA1 = nullptr;
  u16* lA0 = As + w * 1024; u16* lA1 = lA0 + 512;
  const float* F1 = nullptr; const float* F2 = nullptr;
  const int r0 = tid >> 2, ch0 = (tid & 3) * 8;
  if constexpr (ASRC == 0) {
    gA0 = (const u16*)Av + (long)(m0 + srow) * lda + scol;
    gA1 = gA0 + (long)16 * lda;
  } else {
    F1 = (const float*)Av + (long)(m0 + r0) * lda + ch0;
    F2 = (const float*)Av + (long)(m0 + r0 + 64) * lda + ch0;
  }

  for (int k0 = 0; k0 < K; k0 += 32) {
    if constexpr (ASRC == 0) {
      gload16(gA0 + k0, lA0);
      gload16(gA1 + k0, lA1);
      gload16(gB0 + k0, lB0);
      gload16(gB1 + k0, lB1);
      __syncthreads();
    } else {
      float4 p0 = *(const float4*)(F1 + k0);
      float4 p1 = *(const float4*)(F1 + k0 + 4);
      float4 q0 = *(const float4*)(F2 + k0);
      float4 q1 = *(const float4*)(F2 + k0 + 4);
      __syncthreads();  // everyone done with previous tile
      gload16(gB0 + k0, lB0);
      gload16(gB1 + k0, lB1);
      *(uint4*)&As[r0 * 32 + ch0] = cvt8(p0, p1);
      *(uint4*)&As[(r0 + 64) * 32 + ch0] = cvt8(q0, q1);
      __syncthreads();
    }
    bf16x8 bfr[4];
    #pragma unroll
    for (int j = 0; j < 4; j++)
      bfr[j] = *(const bf16x8*)&Bs[(wn + j * 16 + lr) * 32 + quad * 8];
    #pragma unroll
    for (int i = 0; i < 4; i++) {
      bf16x8 af = *(const bf16x8*)&As[(wm + i * 16 + lr) * 32 + quad * 8];
      #pragma unroll
      for (int j = 0; j < 4; j++)
        acc[i][j] = MFMA16(af, bfr[j], acc[i][j]);
    }
    __syncthreads();
  }

  #pragma unroll
  for (int i = 0; i < 4; i++) {
    #pragma unroll
    for (int j = 0; j < 4; j++) {
      #pragma unroll
      for (int r = 0; r < 4; r++) {
        const int gm = m0 + wm + i * 16 + quad * 4 + r;
        const int gn = n0 + wn + j * 16 + lr;
        const long oidx = (long)gm * N + gn;
        float v = acc[i][j][r];
        if constexpr (MODE == 0) {
          v += bias[gn];
          outB[oidx] = f2bf(v);
        } else if constexpr (MODE == 1) {
          v += bias[gn] + aux0[oidx];
          outF[oidx] = v;
        } else if constexpr (MODE == 2) {
          v += bias[gn];
          v = fmaxf(v, 0.f);
          float g2 = aux0[(gm & 63) * 8 + (gn >> 6)];
          outB[oidx] = f2bf(v * g2);
        } else if constexpr (MODE == 3) {
          outF[oidx] += 0.1f * (v + aux0[(gm & 63) * 1024 + gn]);
        } else if constexpr (MODE == 4) {
          v += bias[gn];
          float e = __expf(-1.702f * v);
          v = v * __builtin_amdgcn_rcpf(1.f + e);
          outB[oidx] = f2bf(v);
        } else {
          if (bias) v += bias[gn];
          outF[oidx] += v;
        }
      }
    }
  }
}

// ---------------------------------------------------------------------------
// Fused attention per (b,h): S=QK^T/8 -> softmax -> P*V; O overwrites q-slot.
// qkv: [tok=l*64+b][3072], q@+0, k@+1024, v@+2048, col h*64+d. LDS ~51KB.
// ---------------------------------------------------------------------------
__global__ __launch_bounds__(256) void attn_k(u16* __restrict__ qkv)
{
  __shared__ u16 Vt[64 * 264];
  __shared__ u16 Ps[32 * 264];
  __shared__ float rowstat[64];
  float* red = (float*)Ps;  // red's lifetime ends before Ps is written
  const int bh = blockIdx.x, b = bh >> 4, h = bh & 15;
  const int tid = threadIdx.x, w = tid >> 6, lane = tid & 63;
  const int lr = lane & 15, quad = lane >> 4;
  const long base = (long)b * 3072 + h * 64;

  for (int c = tid; c < 2048; c += 256) {
    int m = c >> 3, ch = (c & 7) * 8;
    uint4 vv = *(const uint4*)(qkv + (long)m * 196608 + base + 2048 + ch);
    const u16* s = (const u16*)&vv;
    #pragma unroll
    for (int t = 0; t < 8; t++) Vt[(ch + t) * 264 + m] = s[t];
  }
  __syncthreads();

  for (int qb = 0; qb < 4; qb++) {
    f32x4 acc[4][4];
    #pragma unroll
    for (int i = 0; i < 4; i++)
      #pragma unroll
      for (int j = 0; j < 4; j++)
        #pragma unroll
        for (int r = 0; r < 4; r++) acc[i][j][r] = 0.f;

    #pragma unroll
    for (int ks = 0; ks < 2; ks++) {
      bf16x8 bfr[4];
      #pragma unroll
      for (int j = 0; j < 4; j++) {
        int key = w * 64 + j * 16 + lr;
        bfr[j] = *(const bf16x8*)(qkv + (long)key * 196608 + base + 1024 + ks * 32 + quad * 8);
      }
      #pragma unroll
      for (int i = 0; i < 4; i++) {
        int gq = qb * 64 + i * 16 + lr;
        bf16x8 af = *(const bf16x8*)(qkv + (long)gq * 196608 + base + ks * 32 + quad * 8);
        #pragma unroll
        for (int j = 0; j < 4; j++)
          acc[i][j] = MFMA16(af, bfr[j], acc[i][j]);
      }
    }

    #pragma unroll
    for (int i = 0; i < 4; i++) {
      #pragma unroll
      for (int r = 0; r < 4; r++) {
        float m = -1e30f;
        #pragma unroll
        for (int j = 0; j < 4; j++) {
          float s = acc[i][j][r] * 0.125f;
          acc[i][j][r] = s;
          m = fmaxf(m, s);
        }
        #pragma unroll
        for (int off = 1; off < 16; off <<= 1) m = fmaxf(m, __shfl_xor(m, off));
        if (lr == 0) red[w * 64 + i * 16 + quad * 4 + r] = m;
      }
    }
    __syncthreads();
    if (tid < 64)
      rowstat[tid] = fmaxf(fmaxf(red[tid], red[64 + tid]),
                           fmaxf(red[128 + tid], red[192 + tid]));
    __syncthreads();

    #pragma unroll
    for (int i = 0; i < 4; i++) {
      #pragma unroll
      for (int r = 0; r < 4; r++) {
        float rm = rowstat[i * 16 + quad * 4 + r];
        float s = 0.f;
        #pragma unroll
        for (int j = 0; j < 4; j++) {
          float e = __expf(acc[i][j][r] - rm);
          acc[i][j][r] = e;
          s += e;
        }
        #pragma unroll
        for (int off = 1; off < 16; off <<= 1) s += __shfl_xor(s, off);
        if (lr == 0) red[w * 64 + i * 16 + quad * 4 + r] = s;
      }
    }
    __syncthreads();
    if (tid < 64)
      rowstat[tid] = red[tid] + red[64 + tid] + red[128 + tid] + red[192 + tid];
    __syncthreads();

    #pragma unroll
    for (int hf = 0; hf < 2; hf++) {
      #pragma unroll
      for (int ii = 0; ii < 2; ii++) {
        int i = hf * 2 + ii;
        #pragma unroll
        for (int r = 0; r < 4; r++) {
          int row = i * 16 + quad * 4 + r;
          float inv = 1.f / rowstat[row];
          #pragma unroll
          for (int j = 0; j < 4; j++)
            Ps[(row - hf * 32) * 264 + w * 64 + j * 16 + lr] =
                f2bf(acc[i][j][r] * inv);
        }
      }
      __syncthreads();
      f32x4 o[2];
      #pragma unroll
      for (int j2 = 0; j2 < 2; j2++)
        #pragma unroll
        for (int r = 0; r < 4; r++) o[j2][r] = 0.f;
      #pragma unroll
      for (int ks = 0; ks < 8; ks++) {
        bf16x8 af = *(const bf16x8*)&Ps[((w >> 1) * 16 + lr) * 264 + ks * 32 + quad * 8];
        #pragma unroll
        for (int j2 = 0; j2 < 2; j2++) {
          int j = (w & 1) * 2 + j2;
          bf16x8 bv = *(const bf16x8*)&Vt[(j * 16 + lr) * 264 + ks * 32 + quad * 8];
          o[j2] = MFMA16(af, bv, o[j2]);
        }
      }
      int l0 = qb * 64 + hf * 32 + (w >> 1) * 16 + quad * 4;
      #pragma unroll
      for (int j2 = 0; j2 < 2; j2++) {
        int j = (w & 1) * 2 + j2;
        #pragma unroll
        for (int r = 0; r < 4; r++)
          qkv[(long)(l0 + r) * 196608 + base + j * 16 + lr] = f2bf(o[j2][r]);
      }
      __syncthreads();
    }
  }
}

// --------------------------- LayerNorm (f32 -> bf16) -----------------------
__global__ __launch_bounds__(256) void ln_k(const float* __restrict__ x,
                                            const float* __restrict__ wt,
                                            const float* __restrict__ bs,
                                            u16* __restrict__ out)
{
  const int tok = blockIdx.x * 4 + (threadIdx.x >> 6);
  const int lane = threadIdx.x & 63;
  const float* xp = x + (long)tok * 1024;
  float4 v[4];
  float s = 0.f, s2 = 0.f;
  #pragma unroll
  for (int t = 0; t < 4; t++) {
    v[t] = *(const float4*)(xp + t * 256 + lane * 4);
    s += v[t].x + v[t].y + v[t].z + v[t].w;
    s2 += v[t].x * v[t].x + v[t].y * v[t].y + v[t].z * v[t].z + v[t].w * v[t].w;
  }
  #pragma unroll
  for (int off = 32; off >= 1; off >>= 1) {
    s += __shfl_xor(s, off);
    s2 += __shfl_xor(s2, off);
  }
  const float m = s * (1.f / 1024.f);
  const float rstd = rsqrtf(s2 * (1.f / 1024.f) - m * m + 1e-5f);
  u16* op = out + (long)tok * 1024;
  #pragma unroll
  for (int t = 0; t < 4; t++) {
    int d = t * 256 + lane * 4;
    float4 wv = *(const float4*)(wt + d);
    float4 bv = *(const float4*)(bs + d);
    union { u16 h[4]; uint2 q; } o;
    o.h[0] = f2bf((v[t].x - m) * rstd * wv.x + bv.x);
    o.h[1] = f2bf((v[t].y - m) * rstd * wv.y + bv.y);
    o.h[2] = f2bf((v[t].z - m) * rstd * wv.z + bv.z);
    o.h[3] = f2bf((v[t].w - m) * rstd * wv.w + bv.w);
    *(uint2*)(op + d) = o.q;
  }
}

// --------------------------- weight converts -------------------------------
__global__ void cvtk(const float* __restrict__ src, u16* __restrict__ dst, int n4)
{
  int i = blockIdx.x * 256 + threadIdx.x;
  if (i >= n4) return;
  float4 v = ((const float4*)src)[i];
  union { u16 h[4]; uint2 q; } o;
  o.h[0] = f2bf(v.x); o.h[1] = f2bf(v.y); o.h[2] = f2bf(v.z); o.h[3] = f2bf(v.w);
  ((uint2*)dst)[i] = o.q;
}

// dst[d*512 + e*64 + r] = up_w[(e*1024 + d)*64 + r]   (up_w is (E,D,R))
__global__ void wupk(const float* __restrict__ up_w, u16* __restrict__ dst)
{
  int i = blockIdx.x * 256 + threadIdx.x;  // 524288
  int r = i & 63, e = (i >> 6) & 7, d = i >> 9;
  dst[i] = f2bf(up_w[(e * 1024 + d) * 64 + r]);
}

// --------------------------- gating ----------------------------------------
__global__ __launch_bounds__(256) void gate_k(const float* __restrict__ x1,
                                              const float* __restrict__ wg,
                                              float* __restrict__ gates)
{
  const int wv = threadIdx.x >> 6, lane = threadIdx.x & 63;
  const int b = blockIdx.x * 4 + wv;
  const float* xp = x1 + (long)b * 1024;
  float lg[8];
  #pragma unroll
  for (int e = 0; e < 8; e++) lg[e] = 0.f;
  for (int i = 0; i < 16; i++) {
    int d = i * 64 + lane;
    float xv = xp[d];
    #pragma unroll
    for (int e = 0; e < 8; e++) lg[e] += xv * wg[d * 8 + e];
  }
  #pragma unroll
  for (int e = 0; e < 8; e++)
    #pragma unroll
    for (int off = 32; off >= 1; off >>= 1) lg[e] += __shfl_xor(lg[e], off);
  if (lane == 0) {
    int e1 = 0; float v1 = lg[0];
    #pragma unroll
    for (int e = 1; e < 8; e++) if (lg[e] > v1) { v1 = lg[e]; e1 = e; }
    int e2 = -1; float v2 = -1e30f;
    #pragma unroll
    for (int e = 0; e < 8; e++) if (e != e1 && lg[e] > v2) { v2 = lg[e]; e2 = e; }
    float ex = __expf(v2 - v1);
    float inv = 1.f / (1.f + ex);
    #pragma unroll
    for (int e = 0; e < 8; e++)
      gates[b * 8 + e] = (e == e1) ? inv : ((e == e2) ? ex * inv : 0.f);
  }
}

__global__ void moe_loss_k(const float* __restrict__ gates, float* __restrict__ out)
{
  if (threadIdx.x != 0) return;
  float imp[8], ld[8];
  for (int e = 0; e < 8; e++) { imp[e] = 0.f; ld[e] = 0.f; }
  for (int b = 0; b < 64; b++)
    for (int e = 0; e < 8; e++) {
      float g = gates[b * 8 + e];
      imp[e] += g;
      if (g > 0.f) ld[e] += 1.f;
    }
  float mi = 0.f, ml = 0.f;
  for (int e = 0; e < 8; e++) { mi += imp[e]; ml += ld[e]; }
  mi *= 0.125f; ml *= 0.125f;
  float vi = 0.f, vl = 0.f;
  for (int e = 0; e < 8; e++) {
    float a = imp[e] - mi; vi += a * a;
    float c = ld[e] - ml; vl += c * c;
  }
  vi *= (1.f / 7.f); vl *= (1.f / 7.f);
  out[0] = 0.01f * (vi / (mi * mi + 1e-10f) + vl / (ml * ml + 1e-10f));
}

// gb[b][d] = sum_e gates[b,e] * up_b[e,d]
__global__ __launch_bounds__(256) void gb_k(const float* __restrict__ gates,
                                            const float* __restrict__ up_b,
                                            float* __restrict__ gb)
{
  int b = blockIdx.x, d0 = threadIdx.x * 4;
  float g[8];
  #pragma unroll
  for (int e = 0; e < 8; e++) g[e] = gates[b * 8 + e];
  float s0 = 0, s1 = 0, s2 = 0, s3 = 0;
  #pragma unroll
  for (int e = 0; e < 8; e++) {
    float4 u = *(const float4*)(up_b + e * 1024 + d0);
    s0 += g[e] * u.x; s1 += g[e] * u.y; s2 += g[e] * u.z; s3 += g[e] * u.w;
  }
  float4 r; r.x = s0; r.y = s1; r.z = s2; r.w = s3;
  *(float4*)(gb + b * 1024 + d0) = r;
}

// ---------------------------------------------------------------------------
extern "C" void kernel_launch(void* const* d_in, const int* in_sizes, int n_in,
                              void* d_out, int out_size, void* d_ws, size_t ws_size,
                              hipStream_t stream)
{
  (void)in_sizes; (void)n_in; (void)out_size;
  const float* x      = (const float*)d_in[0];
  const float* ln1_w  = (const float*)d_in[1];
  const float* ln1_b  = (const float*)d_in[2];
  const float* in_w   = (const float*)d_in[3];
  const float* in_b   = (const float*)d_in[4];
  const float* out_w  = (const float*)d_in[5];
  const float* out_b  = (const float*)d_in[6];
  const float* ln2_w  = (const float*)d_in[7];
  const float* ln2_b  = (const float*)d_in[8];
  const float* fc_w   = (const float*)d_in[9];
  const float* fc_b   = (const float*)d_in[10];
  const float* pj_w   = (const float*)d_in[11];
  const float* pj_b   = (const float*)d_in[12];
  const float* w_gate = (const float*)d_in[13];
  const float* down_w = (const float*)d_in[14];
  const float* down_b = (const float*)d_in[15];
  const float* up_w   = (const float*)d_in[16];
  const float* up_b   = (const float*)d_in[17];
  float* out = (float*)d_out;
  char* ws = (char*)d_ws;

  // ws layout (base footprint ~115 MB, proven), lifetime-aliased
  u16* wb_in   = (u16*)(ws + 0);          // 6 MB   (dead after qkv gemm)
  u16* wb_out  = (u16*)(ws + 6291456);    // 2 MB   (dead after out_proj)
  u16* wb_down = (u16*)(ws + 8388608);    // 1 MB
  u16* wb_up   = (u16*)(ws + 9437184);    // 1 MB
  u16* wb_fc   = (u16*)(ws + 0);          // 8 MB   (aliases in/out, converted late)
  u16* wb_pj   = (u16*)(ws + 10485760);   // 8 MB
  float* gates = (float*)(ws + 19005440); // 2 KB
  float* gb    = (float*)(ws + 19007488); // 256 KB
  u16* qkv     = (u16*)(ws + 19269632);   // 96 MB  (dead after out_proj)
  u16* xln2    = (u16*)(ws + 19269632);   // 32 MB  (alias qkv[0:32M])
  u16* hg      = (u16*)(ws + 52824064);   // 16 MB  (alias qkv[32M:48M])
  u16* h2      = (u16*)(ws + 69601280);   // 32 MB chunked / 128 MB if ws allows
  // xln (LN1 output, bf16) lives in d_out until out_proj overwrites it
  u16* xln = (u16*)d_out;

  const bool big = ws_size >= (size_t)203819008;  // 69601280 + 128 MB

  // phase-1 weight converts
  cvtk<<<3072, 256, 0, stream>>>(in_w, wb_in, 786432);
  cvtk<<<1024, 256, 0, stream>>>(out_w, wb_out, 262144);
  cvtk<<<512, 256, 0, stream>>>(down_w, wb_down, 131072);
  wupk<<<2048, 256, 0, stream>>>(up_w, wb_up);

  // LN1 -> xln (bf16, in d_out); qkv = xln @ in_w^T + in_b
  ln_k<<<4096, 256, 0, stream>>>(x, ln1_w, ln1_b, xln);
  gemm_k<0, 0><<<24 * 128, 256, 0, stream>>>(
      xln, 1024, wb_in, 1024, in_b, nullptr, nullptr, qkv, 3072, 1024);

  // fused attention; O overwrites q-slot of qkv
  attn_k<<<1024, 256, 0, stream>>>(qkv);

  // x1 = O @ out_w^T + out_b + x  -> d_out (f32)
  gemm_k<1, 0><<<8 * 128, 256, 0, stream>>>(
      qkv, 3072, wb_out, 1024, out_b, x, out, nullptr, 1024, 1024);

  // gating on x1 rows 0..63 (token 0 of each sequence)
  gate_k<<<16, 256, 0, stream>>>(out, w_gate, gates);
  moe_loss_k<<<1, 64, 0, stream>>>(gates, out + 16777216);
  gb_k<<<64, 256, 0, stream>>>(gates, up_b, gb);

  // LN2 must see pure x1 (before y accumulates into d_out)
  ln_k<<<4096, 256, 0, stream>>>(out, ln2_w, ln2_b, xln2);

  // adapter: down (relu, *gate) from f32 x1; up accumulates y into d_out
  gemm_k<2, 2><<<4 * 128, 256, 0, stream>>>(
      out, 1024, wb_down, 1024, down_b, gates, nullptr, hg, 512, 1024);
  gemm_k<3, 0><<<8 * 128, 256, 0, stream>>>(
      hg, 512, wb_up, 512, nullptr, gb, out, nullptr, 1024, 512);

  // phase-2 weight converts (overwrite dead phase-1 buffers)
  cvtk<<<4096, 256, 0, stream>>>(fc_w, wb_fc, 1048576);
  cvtk<<<4096, 256, 0, stream>>>(pj_w, wb_pj, 1048576);

  if (big) {
    // single-shot MLP: h2 = QuickGELU(xln2 @ fc_w^T + fc_b); out += h2 @ pj_w^T + pj_b
    gemm_k<4, 0><<<32 * 128, 256, 0, stream>>>(
        xln2, 1024, wb_fc, 1024, fc_b, nullptr, nullptr, h2, 4096, 1024);
    gemm_k<5, 0><<<8 * 128, 256, 0, stream>>>(
        h2, 4096, wb_pj, 4096, pj_b, nullptr, out, nullptr, 1024, 4096);
  } else {
    // 4 K-chunks (proven 115 MB footprint)
    for (int c = 0; c < 4; c++) {
      gemm_k<4, 0><<<8 * 128, 256, 0, stream>>>(
          xln2, 1024, wb_fc + (long)c * 1048576, 1024, fc_b + c * 1024,
          nullptr, nullptr, h2, 1024, 1024);
      gemm_k<5, 0><<<8 * 128, 256, 0, stream>>>(
          h2, 1024, wb_pj + c * 1024, 4096, (c == 0) ? pj_b : nullptr,
          nullptr, out, nullptr, 1024, 1024);
    }
  }
}